// Round 8
// baseline (5424.966 us; speedup 1.0000x reference)
//
#include <hip/hip_runtime.h>
#include <stdint.h>

#define EMBED  512
#define HIDDEN 512
#define VOCAB  32000
#define BATCH  64
#define NPIX   196
#define MAXLEN 32
#define NTILE  500      // 64-col fc tiles
#define PSTRIDE 512     // part row stride (u64), cols [500,512) zeroed
#define NBLK   256

typedef float f32x4 __attribute__((ext_vector_type(4)));
typedef short bf16x8 __attribute__((ext_vector_type(8)));
typedef unsigned short ushort_t;
typedef unsigned long long u64;
typedef u64 u64x2 __attribute__((ext_vector_type(2)));

// ---------- helpers ----------
__device__ __forceinline__ u64 pack_key(float v, int idx) {
    unsigned u = __float_as_uint(v);
    u = (u & 0x80000000u) ? ~u : (u | 0x80000000u);   // monotone sortable map
    return ((u64)u << 32) | (unsigned)(~(unsigned)idx); // smaller idx wins ties
}
__device__ __forceinline__ ushort_t f2bf(float x) {           // round-to-nearest-even
    unsigned u = __float_as_uint(x);
    unsigned r = (u + 0x7fffu + ((u >> 16) & 1u)) >> 16;
    return (ushort_t)r;
}
__device__ __forceinline__ float bf2f(ushort_t h) {
    return __uint_as_float(((unsigned)h) << 16);
}

// ---------- software grid barrier (device scope, XCD-safe) ----------
// bar[0] = arrival count, bar[64] = generation (256B apart).
__device__ __forceinline__ void grid_barrier(unsigned* bar) {
    __syncthreads();
    if (threadIdx.x == 0) {
        __threadfence();   // release prior global writes to agent scope
        unsigned* cnt = bar;
        unsigned* gen = bar + 64;
        unsigned g = __hip_atomic_load(gen, __ATOMIC_RELAXED, __HIP_MEMORY_SCOPE_AGENT);
        unsigned arrived = __hip_atomic_fetch_add(cnt, 1u, __ATOMIC_ACQ_REL, __HIP_MEMORY_SCOPE_AGENT);
        if (arrived == (unsigned)(NBLK - 1)) {
            __hip_atomic_store(cnt, 0u, __ATOMIC_RELAXED, __HIP_MEMORY_SCOPE_AGENT);
            __hip_atomic_fetch_add(gen, 1u, __ATOMIC_RELEASE, __HIP_MEMORY_SCOPE_AGENT);
        } else {
            while (__hip_atomic_load(gen, __ATOMIC_ACQUIRE, __HIP_MEMORY_SCOPE_AGENT) == g)
                __builtin_amdgcn_s_sleep(1);
        }
        __threadfence();
    }
    __syncthreads();
}

__global__ void bar_init(unsigned* bar) {
    bar[0] = 0u;
    bar[64] = 0u;
}

// ---------- the whole decode, one persistent kernel ----------
__global__ __launch_bounds__(256) void decode_all(
    const float* __restrict__ enc,
    const int*   __restrict__ captions,
    const float* __restrict__ emb,
    const float* __restrict__ W_ih, const float* __restrict__ b_ih,
    const float* __restrict__ W_hh, const float* __restrict__ b_hh,
    const float* __restrict__ W_fc, const float* __restrict__ b_fc,
    const float* __restrict__ W_init_h, const float* __restrict__ b_init_h,
    const float* __restrict__ W_init_c, const float* __restrict__ b_init_c,
    float* __restrict__ out,
    float* __restrict__ h0g, float* __restrict__ h1g, float* __restrict__ cbuf,
    ushort_t* __restrict__ h_hi, ushort_t* __restrict__ h_lo,
    u64* __restrict__ part,
    ushort_t* __restrict__ Whi, ushort_t* __restrict__ Wlo,
    unsigned* __restrict__ bar)
{
    __shared__ __align__(16) float red[2][4096];   // fc split-K pair reduce
    __shared__ __align__(16) float ssum[HIDDEN];   // init summary

    const int blk = blockIdx.x, tid = threadIdx.x;
    const int lane = tid & 63, wid = tid >> 6;

    // ======== one-time phase: wsplit (all blocks) ========
    {
        const int nt4 = VOCAB * EMBED / 4;
        for (int i = blk * 256 + tid; i < nt4; i += NBLK * 256) {
            f32x4 w = ((const f32x4*)W_fc)[i];
            ushort_t hi[4], lo[4];
#pragma unroll
            for (int e = 0; e < 4; ++e) {
                hi[e] = f2bf(w[e]);
                lo[e] = f2bf(w[e] - bf2f(hi[e]));
            }
            *(uint64_t*)&Whi[i * 4] = *(const uint64_t*)hi;
            *(uint64_t*)&Wlo[i * 4] = *(const uint64_t*)lo;
        }
    }
    // ======== one-time phase: init (blocks 0..63), part-pad zero (block 64) ========
    if (blk < BATCH) {
        const int b = blk;
        for (int k = tid; k < HIDDEN; k += 256) {
            float s = 0.f;
            const float* p = enc + (size_t)b * NPIX * HIDDEN + k;
            for (int px = 0; px < NPIX; ++px) s += p[(size_t)px * HIDDEN];
            ssum[k] = s * (1.0f / NPIX);
        }
        __syncthreads();
        for (int j = tid; j < HIDDEN; j += 256) {
            const f32x4* wh = (const f32x4*)(W_init_h + (size_t)j * HIDDEN);
            const f32x4* wc = (const f32x4*)(W_init_c + (size_t)j * HIDDEN);
            float ah = 0.f, ac = 0.f;
            for (int k4 = 0; k4 < HIDDEN / 4; ++k4) {
                f32x4 s4 = *(const f32x4*)&ssum[k4 * 4];
                f32x4 a = wh[k4], cc = wc[k4];
                ah += s4[0]*a[0] + s4[1]*a[1] + s4[2]*a[2] + s4[3]*a[3];
                ac += s4[0]*cc[0] + s4[1]*cc[1] + s4[2]*cc[2] + s4[3]*cc[3];
            }
            h0g[b * HIDDEN + j] = ah + b_init_h[j];
            cbuf[b * HIDDEN + j] = ac + b_init_c[j];
        }
        f32x4* o4 = (f32x4*)(out + (size_t)b * MAXLEN * VOCAB);
        f32x4 z = {0.f, 0.f, 0.f, 0.f};
        for (int i = tid; i < VOCAB / 4; i += 256) __builtin_nontemporal_store(z, &o4[i]);
    } else if (blk == BATCH) {
        for (int i = tid; i < BATCH * (PSTRIDE - NTILE); i += 256) {
            const int row = i / (PSTRIDE - NTILE), c = i % (PSTRIDE - NTILE);
            part[(size_t)row * PSTRIDE + NTILE + c] = 0ull;
        }
    }
    grid_barrier(bar);

    // ======== 31 decode steps ========
    for (int t = 0; t < MAXLEN - 1; ++t) {
        const float* hin  = (t & 1) ? h1g : h0g;
        float*       hout = (t & 1) ? h0g : h1g;

        // ---------- LSTM phase (all 256 blocks; u0 = blk*2) ----------
        {
            const int u0 = blk * 2;
            const int b = tid >> 2, q = tid & 3;

            int tok;
            if (t == 0) {
                tok = captions[b * MAXLEN];
            } else {
                const u64x2* pr = (const u64x2*)(part + (size_t)b * PSTRIDE + q * 128);
                u64 km = 0ull;
#pragma unroll 8
                for (int i = 0; i < 64; ++i) {
                    u64x2 kv = pr[i];
                    u64 k0 = kv.x > kv.y ? kv.x : kv.y;
                    km = k0 > km ? k0 : km;
                }
                u64 o1 = __shfl_xor(km, 1, 64); km = km > o1 ? km : o1;
                u64 o2 = __shfl_xor(km, 2, 64); km = km > o2 ? km : o2;
                tok = (int)(~(unsigned)(km & 0xffffffffull));
            }

            const f32x4* x4 = (const f32x4*)(emb + (size_t)tok * EMBED);
            const f32x4* h4 = (const f32x4*)(hin + b * HIDDEN);
            const int j_0 = q * HIDDEN + u0;
            const f32x4* wiA = (const f32x4*)(W_ih + (size_t)j_0 * EMBED);
            const f32x4* wiB = wiA + EMBED / 4;
            const f32x4* whA = (const f32x4*)(W_hh + (size_t)j_0 * HIDDEN);
            const f32x4* whB = whA + HIDDEN / 4;

            float a0 = 0.f, a1 = 0.f;
#pragma unroll 4
            for (int k4 = 0; k4 < EMBED / 4; ++k4) {
                f32x4 xv = x4[k4], hv = h4[k4];
                f32x4 wA = wiA[k4], wB = wiB[k4], vA = whA[k4], vB = whB[k4];
                a0 += xv[0]*wA[0] + xv[1]*wA[1] + xv[2]*wA[2] + xv[3]*wA[3]
                    + hv[0]*vA[0] + hv[1]*vA[1] + hv[2]*vA[2] + hv[3]*vA[3];
                a1 += xv[0]*wB[0] + xv[1]*wB[1] + xv[2]*wB[2] + xv[3]*wB[3]
                    + hv[0]*vB[0] + hv[1]*vB[1] + hv[2]*vB[2] + hv[3]*vB[3];
            }
            a0 += b_ih[j_0] + b_hh[j_0];
            a1 += b_ih[j_0 + 1] + b_hh[j_0 + 1];

            const int base = lane & ~3;
#pragma unroll
            for (int uu = 0; uu < 2; ++uu) {
                float g  = (uu == 0) ? a0 : a1;
                float gi = __shfl(g, base + 0, 64);
                float gf = __shfl(g, base + 1, 64);
                float gg = __shfl(g, base + 2, 64);
                float go = __shfl(g, base + 3, 64);
                if (q == uu) {
                    const int u = u0 + uu;
                    float i_ = 1.f / (1.f + expf(-gi));
                    float f_ = 1.f / (1.f + expf(-gf));
                    float o_ = 1.f / (1.f + expf(-go));
                    float g_ = tanhf(gg);
                    float cv = cbuf[b * HIDDEN + u];
                    float c2 = f_ * cv + i_ * g_;
                    float h2 = o_ * tanhf(c2);
                    cbuf[b * HIDDEN + u] = c2;
                    hout[b * HIDDEN + u] = h2;
                    ushort_t hh = f2bf(h2);
                    h_hi[b * HIDDEN + u] = hh;
                    h_lo[b * HIDDEN + u] = f2bf(h2 - bf2f(hh));
                }
            }
        }
        grid_barrier(bar);

        // ---------- FC phase (blocks 0..249; 2 tiles/block, split-K x2) ----------
        if (blk < NTILE / 2) {
            const int tileSel = wid >> 1, khalf = wid & 1;
            const int tileIdx = blk * 2 + tileSel;
            const int n0 = tileIdx * 64;
            const int r16 = lane & 15, g = lane >> 4;

            f32x4 acc[4][4];
#pragma unroll
            for (int i = 0; i < 4; ++i)
#pragma unroll
                for (int j = 0; j < 4; ++j) acc[i][j] = (f32x4){0.f, 0.f, 0.f, 0.f};

            const ushort_t* ha = h_hi + (size_t)r16 * EMBED + g * 8;
            const ushort_t* la = h_lo + (size_t)r16 * EMBED + g * 8;
            const ushort_t* hb = Whi + (size_t)(n0 + r16) * EMBED + g * 8;
            const ushort_t* lb = Wlo + (size_t)(n0 + r16) * EMBED + g * 8;

            const int kb0 = khalf * 8;
            for (int kb = kb0; kb < kb0 + 8; ++kb) {
                const int ko = kb * 32;
                bf16x8 Ah[4], Al[4], Bh[4], Bl[4];
#pragma unroll
                for (int mt = 0; mt < 4; ++mt) {
                    Ah[mt] = *(const bf16x8*)(ha + (size_t)mt * 16 * EMBED + ko);
                    Al[mt] = *(const bf16x8*)(la + (size_t)mt * 16 * EMBED + ko);
                }
#pragma unroll
                for (int nt = 0; nt < 4; ++nt) {
                    Bh[nt] = *(const bf16x8*)(hb + (size_t)nt * 16 * EMBED + ko);
                    Bl[nt] = *(const bf16x8*)(lb + (size_t)nt * 16 * EMBED + ko);
                }
#pragma unroll
                for (int mt = 0; mt < 4; ++mt)
#pragma unroll
                    for (int nt = 0; nt < 4; ++nt) {
                        acc[mt][nt] = __builtin_amdgcn_mfma_f32_16x16x32_bf16(Al[mt], Bh[nt], acc[mt][nt], 0, 0, 0);
                        acc[mt][nt] = __builtin_amdgcn_mfma_f32_16x16x32_bf16(Ah[mt], Bl[nt], acc[mt][nt], 0, 0, 0);
                        acc[mt][nt] = __builtin_amdgcn_mfma_f32_16x16x32_bf16(Ah[mt], Bh[nt], acc[mt][nt], 0, 0, 0);
                    }
            }

            if (khalf) {
#pragma unroll
                for (int mt = 0; mt < 4; ++mt)
#pragma unroll
                    for (int nt = 0; nt < 4; ++nt)
#pragma unroll
                        for (int reg = 0; reg < 4; ++reg)
                            red[tileSel][((mt * 4 + nt) * 4 + reg) * 64 + lane] = acc[mt][nt][reg];
            }
            __syncthreads();
            if (!khalf) {
#pragma unroll
                for (int mt = 0; mt < 4; ++mt)
#pragma unroll
                    for (int nt = 0; nt < 4; ++nt)
#pragma unroll
                        for (int reg = 0; reg < 4; ++reg)
                            acc[mt][nt][reg] += red[tileSel][((mt * 4 + nt) * 4 + reg) * 64 + lane];

                float bias[4];
#pragma unroll
                for (int nt = 0; nt < 4; ++nt) bias[nt] = b_fc[n0 + nt * 16 + r16];

#pragma unroll
                for (int mt = 0; mt < 4; ++mt)
#pragma unroll
                    for (int reg = 0; reg < 4; ++reg) {
                        const int row = mt * 16 + g * 4 + reg;
                        float* op = &out[(size_t)row * (MAXLEN * VOCAB) + (size_t)(t + 1) * VOCAB];
                        u64 km = 0ull;
#pragma unroll
                        for (int nt = 0; nt < 4; ++nt) {
                            const int col = n0 + nt * 16 + r16;
                            float v = acc[mt][nt][reg] + bias[nt];
                            __builtin_nontemporal_store(v, op + col);
                            u64 kk = pack_key(v, col);
                            km = kk > km ? kk : km;
                        }
#pragma unroll
                        for (int msk = 8; msk >= 1; msk >>= 1) {
                            u64 o = __shfl_xor(km, msk, 64);
                            km = km > o ? km : o;
                        }
                        if (r16 == 0) part[(size_t)row * PSTRIDE + tileIdx] = km;
                    }
            }
        }
        grid_barrier(bar);
    }
}

extern "C" void kernel_launch(void* const* d_in, const int* in_sizes, int n_in,
                              void* d_out, int out_size, void* d_ws, size_t ws_size,
                              hipStream_t stream) {
    const float* enc       = (const float*)d_in[0];
    const int*   captions  = (const int*)  d_in[1];
    const float* emb       = (const float*)d_in[2];
    const float* W_ih      = (const float*)d_in[3];
    const float* b_ih      = (const float*)d_in[4];
    const float* W_hh      = (const float*)d_in[5];
    const float* b_hh      = (const float*)d_in[6];
    const float* W_fc      = (const float*)d_in[7];
    const float* b_fc      = (const float*)d_in[8];
    const float* W_init_h  = (const float*)d_in[9];
    const float* b_init_h  = (const float*)d_in[10];
    const float* W_init_c  = (const float*)d_in[11];
    const float* b_init_c  = (const float*)d_in[12];
    float* out = (float*)d_out;

    float* ws = (float*)d_ws;
    float* h0g  = ws;                                        // 32768 f32
    float* h1g  = ws + 32768;                                // 32768 f32
    float* cbuf = ws + 65536;                                // 32768 f32
    unsigned* bar = (unsigned*)(ws + 98304);                 // 2 u32 (256B apart), region [98304,98560)
    ushort_t* h_hi = (ushort_t*)(ws + 98560);                // 64*512 bf16
    ushort_t* h_lo = (ushort_t*)(ws + 114944);               // 64*512 bf16
    u64* part = (u64*)(ws + 131328);                         // 64*512 u64
    ushort_t* Whi = (ushort_t*)(ws + 196864);                // 32000*512 bf16
    ushort_t* Wlo = (ushort_t*)(ws + 8388864);               // 32000*512 bf16

    bar_init<<<1, 1, 0, stream>>>(bar);
    decode_all<<<NBLK, 256, 0, stream>>>(
        enc, captions, emb, W_ih, b_ih, W_hh, b_hh, W_fc, b_fc,
        W_init_h, b_init_h, W_init_c, b_init_c,
        out, h0g, h1g, cbuf, h_hi, h_lo, part, Whi, Wlo, bar);
}

// Round 10
// 4142.765 us; speedup vs baseline: 1.3095x; 1.3095x over previous
//
#include <hip/hip_runtime.h>
#include <stdint.h>

#define EMBED  512
#define HIDDEN 512
#define VOCAB  32000
#define BATCH  64
#define NPIX   196
#define MAXLEN 32
#define NTILE  500      // 64-col fc tiles
#define PSTRIDE 512     // part row stride (u64), cols [500,512) zeroed
#define NBLK   256
#define NGRP   16       // 16 groups x 16 blocks
#define NBAR   64       // barrier slots (1 init + 62 step barriers used)

typedef float f32x4 __attribute__((ext_vector_type(4)));
typedef short bf16x8 __attribute__((ext_vector_type(8)));
typedef unsigned short ushort_t;
typedef unsigned long long u64;
typedef u64 u64x2 __attribute__((ext_vector_type(2)));

// ---------- helpers ----------
__device__ __forceinline__ u64 pack_key(float v, int idx) {
    unsigned u = __float_as_uint(v);
    u = (u & 0x80000000u) ? ~u : (u | 0x80000000u);   // monotone sortable map
    return ((u64)u << 32) | (unsigned)(~(unsigned)idx); // smaller idx wins ties
}
__device__ __forceinline__ ushort_t f2bf(float x) {           // round-to-nearest-even
    unsigned u = __float_as_uint(x);
    unsigned r = (u + 0x7fffu + ((u >> 16) & 1u)) >> 16;
    return (ushort_t)r;
}
__device__ __forceinline__ float bf2f(ushort_t h) {
    return __uint_as_float(((unsigned)h) << 16);
}

// ---------- tree grid barrier: slot-per-instance, RMW polls, XCD-safe ----------
// barws layout (u32): gcnt[k][grp] @ (k*16+grp)*16 ; rcnt[k] @ 16384 + k*16 ;
// gflag[k][grp] @ 17408 + (k*16+grp)*16. Counters only increase; no resets,
// no generation race. Polls are fetch_add(,0) RMWs -> always read the
// coherence point (no per-poll cache invalidation, no stale-L2 deadlock).
__device__ __forceinline__ void grid_barrier(unsigned* barws, int k) {
    __syncthreads();
    if (threadIdx.x == 0) {
        const int grp = blockIdx.x >> 4;
        const bool leader = (blockIdx.x & 15) == 0;
        unsigned* gc = barws + (k * NGRP + grp) * 16;
        unsigned* rc = barws + 16384 + k * 16;
        unsigned* gf = barws + 17408 + (k * NGRP + grp) * 16;
        __threadfence();   // release this block's phase writes (once)
        if (!leader) {
            __hip_atomic_fetch_add(gc, 1u, __ATOMIC_RELAXED, __HIP_MEMORY_SCOPE_AGENT);
            while (__hip_atomic_fetch_add(gf, 0u, __ATOMIC_RELAXED, __HIP_MEMORY_SCOPE_AGENT) == 0u)
                __builtin_amdgcn_s_sleep(2);
        } else {
            while (__hip_atomic_fetch_add(gc, 0u, __ATOMIC_RELAXED, __HIP_MEMORY_SCOPE_AGENT) < 15u)
                __builtin_amdgcn_s_sleep(1);
            __hip_atomic_fetch_add(rc, 1u, __ATOMIC_RELAXED, __HIP_MEMORY_SCOPE_AGENT);
            while (__hip_atomic_fetch_add(rc, 0u, __ATOMIC_RELAXED, __HIP_MEMORY_SCOPE_AGENT) < (unsigned)NGRP)
                __builtin_amdgcn_s_sleep(1);
            __hip_atomic_fetch_add(gf, 1u, __ATOMIC_RELAXED, __HIP_MEMORY_SCOPE_AGENT);
        }
        __threadfence();   // acquire other blocks' phase writes (once)
    }
    __syncthreads();
}

__global__ void bar_init(unsigned* barws) {
    const int i = blockIdx.x * 256 + threadIdx.x;
    if (i < 33792) barws[i] = 0u;   // 132KB of barrier slots
}

// ---------- the whole decode, one persistent kernel ----------
__global__ __launch_bounds__(256) void decode_all(
    const float* __restrict__ enc,
    const int*   __restrict__ captions,
    const float* __restrict__ emb,
    const float* __restrict__ W_ih, const float* __restrict__ b_ih,
    const float* __restrict__ W_hh, const float* __restrict__ b_hh,
    const float* __restrict__ W_fc, const float* __restrict__ b_fc,
    const float* __restrict__ W_init_h, const float* __restrict__ b_init_h,
    const float* __restrict__ W_init_c, const float* __restrict__ b_init_c,
    float* __restrict__ out,
    float* __restrict__ h0g, float* __restrict__ h1g, float* __restrict__ cbuf,
    ushort_t* __restrict__ h_hi, ushort_t* __restrict__ h_lo,
    u64* __restrict__ part,
    ushort_t* __restrict__ Whi, ushort_t* __restrict__ Wlo,
    unsigned* __restrict__ barws)
{
    __shared__ __align__(16) float red[2][4096];   // fc split-K pair reduce
    __shared__ __align__(16) float ssum[HIDDEN];   // init summary

    const int blk = blockIdx.x, tid = threadIdx.x;
    const int lane = tid & 63, wid = tid >> 6;

    // ======== one-time phase: wsplit (all blocks) ========
    {
        const int nt4 = VOCAB * EMBED / 4;
        for (int i = blk * 256 + tid; i < nt4; i += NBLK * 256) {
            f32x4 w = ((const f32x4*)W_fc)[i];
            ushort_t hi[4], lo[4];
#pragma unroll
            for (int e = 0; e < 4; ++e) {
                hi[e] = f2bf(w[e]);
                lo[e] = f2bf(w[e] - bf2f(hi[e]));
            }
            *(uint64_t*)&Whi[i * 4] = *(const uint64_t*)hi;
            *(uint64_t*)&Wlo[i * 4] = *(const uint64_t*)lo;
        }
    }
    // ======== one-time phase: init (blocks 0..63), part-pad zero (block 64) ========
    if (blk < BATCH) {
        const int b = blk;
        for (int k = tid; k < HIDDEN; k += 256) {
            float s = 0.f;
            const float* p = enc + (size_t)b * NPIX * HIDDEN + k;
            for (int px = 0; px < NPIX; ++px) s += p[(size_t)px * HIDDEN];
            ssum[k] = s * (1.0f / NPIX);
        }
        __syncthreads();
        for (int j = tid; j < HIDDEN; j += 256) {
            const f32x4* wh = (const f32x4*)(W_init_h + (size_t)j * HIDDEN);
            const f32x4* wc = (const f32x4*)(W_init_c + (size_t)j * HIDDEN);
            float ah = 0.f, ac = 0.f;
            for (int k4 = 0; k4 < HIDDEN / 4; ++k4) {
                f32x4 s4 = *(const f32x4*)&ssum[k4 * 4];
                f32x4 a = wh[k4], cc = wc[k4];
                ah += s4[0]*a[0] + s4[1]*a[1] + s4[2]*a[2] + s4[3]*a[3];
                ac += s4[0]*cc[0] + s4[1]*cc[1] + s4[2]*cc[2] + s4[3]*cc[3];
            }
            h0g[b * HIDDEN + j] = ah + b_init_h[j];
            cbuf[b * HIDDEN + j] = ac + b_init_c[j];
        }
        f32x4* o4 = (f32x4*)(out + (size_t)b * MAXLEN * VOCAB);
        f32x4 z = {0.f, 0.f, 0.f, 0.f};
        for (int i = tid; i < VOCAB / 4; i += 256) __builtin_nontemporal_store(z, &o4[i]);
    } else if (blk == BATCH) {
        for (int i = tid; i < BATCH * (PSTRIDE - NTILE); i += 256) {
            const int row = i / (PSTRIDE - NTILE), c = i % (PSTRIDE - NTILE);
            part[(size_t)row * PSTRIDE + NTILE + c] = 0ull;
        }
    }
    grid_barrier(barws, 0);

    // ======== 31 decode steps ========
    for (int t = 0; t < MAXLEN - 1; ++t) {
        const float* hin  = (t & 1) ? h1g : h0g;
        float*       hout = (t & 1) ? h0g : h1g;

        // ---------- LSTM phase (all 256 blocks; u0 = blk*2) ----------
        {
            const int u0 = blk * 2;
            const int b = tid >> 2, q = tid & 3;

            int tok;
            if (t == 0) {
                tok = captions[b * MAXLEN];
            } else {
                const u64x2* pr = (const u64x2*)(part + (size_t)b * PSTRIDE + q * 128);
                u64 km = 0ull;
#pragma unroll 8
                for (int i = 0; i < 64; ++i) {
                    u64x2 kv = pr[i];
                    u64 k0 = kv.x > kv.y ? kv.x : kv.y;
                    km = k0 > km ? k0 : km;
                }
                u64 o1 = __shfl_xor(km, 1, 64); km = km > o1 ? km : o1;
                u64 o2 = __shfl_xor(km, 2, 64); km = km > o2 ? km : o2;
                tok = (int)(~(unsigned)(km & 0xffffffffull));
            }

            const f32x4* x4 = (const f32x4*)(emb + (size_t)tok * EMBED);
            const f32x4* h4 = (const f32x4*)(hin + b * HIDDEN);
            const int j_0 = q * HIDDEN + u0;
            const f32x4* wiA = (const f32x4*)(W_ih + (size_t)j_0 * EMBED);
            const f32x4* wiB = wiA + EMBED / 4;
            const f32x4* whA = (const f32x4*)(W_hh + (size_t)j_0 * HIDDEN);
            const f32x4* whB = whA + HIDDEN / 4;

            float a0 = 0.f, a1 = 0.f;
#pragma unroll 4
            for (int k4 = 0; k4 < EMBED / 4; ++k4) {
                f32x4 xv = x4[k4], hv = h4[k4];
                f32x4 wA = wiA[k4], wB = wiB[k4], vA = whA[k4], vB = whB[k4];
                a0 += xv[0]*wA[0] + xv[1]*wA[1] + xv[2]*wA[2] + xv[3]*wA[3]
                    + hv[0]*vA[0] + hv[1]*vA[1] + hv[2]*vA[2] + hv[3]*vA[3];
                a1 += xv[0]*wB[0] + xv[1]*wB[1] + xv[2]*wB[2] + xv[3]*wB[3]
                    + hv[0]*vB[0] + hv[1]*vB[1] + hv[2]*vB[2] + hv[3]*vB[3];
            }
            a0 += b_ih[j_0] + b_hh[j_0];
            a1 += b_ih[j_0 + 1] + b_hh[j_0 + 1];

            const int base = lane & ~3;
#pragma unroll
            for (int uu = 0; uu < 2; ++uu) {
                float g  = (uu == 0) ? a0 : a1;
                float gi = __shfl(g, base + 0, 64);
                float gf = __shfl(g, base + 1, 64);
                float gg = __shfl(g, base + 2, 64);
                float go = __shfl(g, base + 3, 64);
                if (q == uu) {
                    const int u = u0 + uu;
                    float i_ = 1.f / (1.f + expf(-gi));
                    float f_ = 1.f / (1.f + expf(-gf));
                    float o_ = 1.f / (1.f + expf(-go));
                    float g_ = tanhf(gg);
                    float cv = cbuf[b * HIDDEN + u];
                    float c2 = f_ * cv + i_ * g_;
                    float h2 = o_ * tanhf(c2);
                    cbuf[b * HIDDEN + u] = c2;
                    hout[b * HIDDEN + u] = h2;
                    ushort_t hh = f2bf(h2);
                    h_hi[b * HIDDEN + u] = hh;
                    h_lo[b * HIDDEN + u] = f2bf(h2 - bf2f(hh));
                }
            }
        }
        grid_barrier(barws, 1 + 2 * t);

        // ---------- FC phase (blocks 0..249; 2 tiles/block, split-K x2) ----------
        if (blk < NTILE / 2) {
            const int tileSel = wid >> 1, khalf = wid & 1;
            const int tileIdx = blk * 2 + tileSel;
            const int n0 = tileIdx * 64;
            const int r16 = lane & 15, g = lane >> 4;

            f32x4 acc[4][4];
#pragma unroll
            for (int i = 0; i < 4; ++i)
#pragma unroll
                for (int j = 0; j < 4; ++j) acc[i][j] = (f32x4){0.f, 0.f, 0.f, 0.f};

            const ushort_t* ha = h_hi + (size_t)r16 * EMBED + g * 8;
            const ushort_t* la = h_lo + (size_t)r16 * EMBED + g * 8;
            const ushort_t* hb = Whi + (size_t)(n0 + r16) * EMBED + g * 8;
            const ushort_t* lb = Wlo + (size_t)(n0 + r16) * EMBED + g * 8;

            const int kb0 = khalf * 8;
            for (int kb = kb0; kb < kb0 + 8; ++kb) {
                const int ko = kb * 32;
                bf16x8 Ah[4], Al[4], Bh[4], Bl[4];
#pragma unroll
                for (int mt = 0; mt < 4; ++mt) {
                    Ah[mt] = *(const bf16x8*)(ha + (size_t)mt * 16 * EMBED + ko);
                    Al[mt] = *(const bf16x8*)(la + (size_t)mt * 16 * EMBED + ko);
                }
#pragma unroll
                for (int nt = 0; nt < 4; ++nt) {
                    Bh[nt] = *(const bf16x8*)(hb + (size_t)nt * 16 * EMBED + ko);
                    Bl[nt] = *(const bf16x8*)(lb + (size_t)nt * 16 * EMBED + ko);
                }
#pragma unroll
                for (int mt = 0; mt < 4; ++mt)
#pragma unroll
                    for (int nt = 0; nt < 4; ++nt) {
                        acc[mt][nt] = __builtin_amdgcn_mfma_f32_16x16x32_bf16(Al[mt], Bh[nt], acc[mt][nt], 0, 0, 0);
                        acc[mt][nt] = __builtin_amdgcn_mfma_f32_16x16x32_bf16(Ah[mt], Bl[nt], acc[mt][nt], 0, 0, 0);
                        acc[mt][nt] = __builtin_amdgcn_mfma_f32_16x16x32_bf16(Ah[mt], Bh[nt], acc[mt][nt], 0, 0, 0);
                    }
            }

            if (khalf) {
#pragma unroll
                for (int mt = 0; mt < 4; ++mt)
#pragma unroll
                    for (int nt = 0; nt < 4; ++nt)
#pragma unroll
                        for (int reg = 0; reg < 4; ++reg)
                            red[tileSel][((mt * 4 + nt) * 4 + reg) * 64 + lane] = acc[mt][nt][reg];
            }
            __syncthreads();
            if (!khalf) {
#pragma unroll
                for (int mt = 0; mt < 4; ++mt)
#pragma unroll
                    for (int nt = 0; nt < 4; ++nt)
#pragma unroll
                        for (int reg = 0; reg < 4; ++reg)
                            acc[mt][nt][reg] += red[tileSel][((mt * 4 + nt) * 4 + reg) * 64 + lane];

                float bias[4];
#pragma unroll
                for (int nt = 0; nt < 4; ++nt) bias[nt] = b_fc[n0 + nt * 16 + r16];

#pragma unroll
                for (int mt = 0; mt < 4; ++mt)
#pragma unroll
                    for (int reg = 0; reg < 4; ++reg) {
                        const int row = mt * 16 + g * 4 + reg;
                        float* op = &out[(size_t)row * (MAXLEN * VOCAB) + (size_t)(t + 1) * VOCAB];
                        u64 km = 0ull;
#pragma unroll
                        for (int nt = 0; nt < 4; ++nt) {
                            const int col = n0 + nt * 16 + r16;
                            float v = acc[mt][nt][reg] + bias[nt];
                            __builtin_nontemporal_store(v, op + col);
                            u64 kk = pack_key(v, col);
                            km = kk > km ? kk : km;
                        }
#pragma unroll
                        for (int msk = 8; msk >= 1; msk >>= 1) {
                            u64 o = __shfl_xor(km, msk, 64);
                            km = km > o ? km : o;
                        }
                        if (r16 == 0) part[(size_t)row * PSTRIDE + tileIdx] = km;
                    }
            }
        }
        grid_barrier(barws, 2 + 2 * t);
    }
}

extern "C" void kernel_launch(void* const* d_in, const int* in_sizes, int n_in,
                              void* d_out, int out_size, void* d_ws, size_t ws_size,
                              hipStream_t stream) {
    const float* enc       = (const float*)d_in[0];
    const int*   captions  = (const int*)  d_in[1];
    const float* emb       = (const float*)d_in[2];
    const float* W_ih      = (const float*)d_in[3];
    const float* b_ih      = (const float*)d_in[4];
    const float* W_hh      = (const float*)d_in[5];
    const float* b_hh      = (const float*)d_in[6];
    const float* W_fc      = (const float*)d_in[7];
    const float* b_fc      = (const float*)d_in[8];
    const float* W_init_h  = (const float*)d_in[9];
    const float* b_init_h  = (const float*)d_in[10];
    const float* W_init_c  = (const float*)d_in[11];
    const float* b_init_c  = (const float*)d_in[12];
    float* out = (float*)d_out;

    char* wsb = (char*)d_ws;
    float* h0g  = (float*)(wsb + 0);            // 131072B
    float* h1g  = (float*)(wsb + 131072);       // 131072B
    float* cbuf = (float*)(wsb + 262144);       // 131072B
    ushort_t* h_hi = (ushort_t*)(wsb + 393216); // 65536B
    ushort_t* h_lo = (ushort_t*)(wsb + 458752); // 65536B
    u64* part = (u64*)(wsb + 524288);           // 262144B -> ends 786432
    unsigned* barws = (unsigned*)(wsb + 786432);// 135168B -> ends 921600
    ushort_t* Whi = (ushort_t*)(wsb + 1048576); // 32768000B -> ends 33816576
    ushort_t* Wlo = (ushort_t*)(wsb + 33816576);// 32768000B -> ends 66584576

    bar_init<<<132, 256, 0, stream>>>(barws);
    decode_all<<<NBLK, 256, 0, stream>>>(
        enc, captions, emb, W_ih, b_ih, W_hh, b_hh, W_fc, b_fc,
        W_init_h, b_init_h, W_init_c, b_init_c,
        out, h0g, h1g, cbuf, h_hi, h_lo, part, Whi, Wlo, barws);
}